// Round 6
// baseline (370.886 us; speedup 1.0000x reference)
//
#include <hip/hip_runtime.h>

#define D 256
#define H 256
#define O 24
#define R 32          // rows per block
#define T 512         // 8 waves; L1/L2: wave = 32 rows x 32 cols (one 32x32 tile)
#define PW 264        // bf16 row stride for piece buffers
#define PS (R * PW)   // piece stride in ushort

typedef __attribute__((ext_vector_type(4))) float f32x4;
typedef __attribute__((ext_vector_type(16))) float f32x16;
typedef __attribute__((ext_vector_type(4))) unsigned short us4;
typedef __attribute__((ext_vector_type(8))) unsigned short us8;
typedef __attribute__((ext_vector_type(8))) __bf16 bf16x8;
typedef __attribute__((ext_vector_type(4))) unsigned int u32x4;

// d_ws layout (ushort units):
//   wf1 @ 0 (384 KB, 32x32x16-format) | wf2 @ 196608 (same) | wf3 @ 393216 (48 KB, 16x16x32-format)
// 32x32 tile(ks,nt) base = ((ks*8+nt)*3 + p)*512 ; 16x16 tile(kb,nb) base = ((kb*2+nb)*3 + p)*512
#define WF2_OFF 196608
#define WF3_OFF 393216

// Exact 3-piece bf16 split. (__bf16) cast = HW RNE (v_cvt_pk_bf16_f32) — bit-identical
// to the previous manual add-shift RNE for all non-NaN inputs; residuals exact (Fast2Sum).
__device__ __forceinline__ void split3(float v, unsigned short& h, unsigned short& m,
                                       unsigned short& l) {
    __bf16 hb = (__bf16)v;
    float r = v - (float)hb;
    __bf16 mb = (__bf16)r;
    float r2 = r - (float)mb;
    __bf16 lb = (__bf16)r2;
    h = __builtin_bit_cast(unsigned short, hb);
    m = __builtin_bit_cast(unsigned short, mb);
    l = __builtin_bit_cast(unsigned short, lb);
}

__device__ __forceinline__ f32x4 mfma16(us8 a, us8 b, f32x4 c) {
    return __builtin_amdgcn_mfma_f32_16x16x32_bf16(
        __builtin_bit_cast(bf16x8, a), __builtin_bit_cast(bf16x8, b), c, 0, 0, 0);
}
__device__ __forceinline__ f32x16 mfma32(us8 a, us8 b, f32x16 c) {
    return __builtin_amdgcn_mfma_f32_32x32x16_bf16(
        __builtin_bit_cast(bf16x8, a), __builtin_bit_cast(bf16x8, b), c, 0, 0, 0);
}

// 6-pass fp32-accurate product, weights as A-operand, activations as B-operand:
// wh*ah + wh*am + wh*al + wm*ah + wm*am + wl*ah  (covers all terms >= ~2^-27 rel)
__device__ __forceinline__ f32x4 mfma6s(const us8* wgt, const us8* act, f32x4 c) {
    c = mfma16(wgt[0], act[0], c);
    c = mfma16(wgt[0], act[1], c);
    c = mfma16(wgt[0], act[2], c);
    c = mfma16(wgt[1], act[0], c);
    c = mfma16(wgt[1], act[1], c);
    c = mfma16(wgt[2], act[0], c);
    return c;
}
__device__ __forceinline__ f32x16 mfma6w(const us8* wgt, const us8* act, f32x16 c) {
    c = mfma32(wgt[0], act[0], c);
    c = mfma32(wgt[0], act[1], c);
    c = mfma32(wgt[0], act[2], c);
    c = mfma32(wgt[1], act[0], c);
    c = mfma32(wgt[1], act[1], c);
    c = mfma32(wgt[2], act[0], c);
    return c;
}

// ---- pre-split weights into fragment-linear bf16 pieces ----
// W1/W2: 32x32x16 B-operand format: tile(ks,nt): lane l -> n = nt*32+(l&31),
//   elems j: k = ks*16 + (l>>5)*8 + j.  W3: old 16x16x32 format (unchanged).
__global__ __launch_bounds__(64) void split_w(
    const float* __restrict__ W1, const float* __restrict__ W2,
    const float* __restrict__ W3, unsigned short* __restrict__ wf)
{
    const int bid = blockIdx.x;        // 0..271
    const int lane = threadIdx.x;      // 0..63
    us8 ph, pm, pl;
    if (bid < 256) {
        const int mat = bid >> 7, tid = bid & 127;
        const int ks = tid >> 3, nt = tid & 7;
        const float* src = mat ? W2 : W1;
        unsigned short* dst = wf + (mat ? WF2_OFF : 0);
        const int n = nt * 32 + (lane & 31);
        const int k0 = ks * 16 + (lane >> 5) * 8;
        #pragma unroll
        for (int j = 0; j < 8; ++j) {
            unsigned short h, m, l; split3(src[(size_t)(k0 + j) * H + n], h, m, l);
            ph[j] = h; pm[j] = m; pl[j] = l;
        }
        const size_t base = ((size_t)(ks * 8 + nt) * 3) * 512 + (size_t)lane * 8;
        *(us8*)(dst + base)        = ph;
        *(us8*)(dst + base + 512)  = pm;
        *(us8*)(dst + base + 1024) = pl;
    } else {
        const int b = bid - 256, kb = b >> 1, nb = b & 1;
        const int q = lane >> 4, ln = lane & 15;
        const int n = nb * 16 + ln;
        #pragma unroll
        for (int j = 0; j < 8; ++j) {
            const int k = kb * 32 + q * 8 + j;
            float v = (n < O) ? W3[(size_t)k * O + n] : 0.f;
            unsigned short h, m, l; split3(v, h, m, l);
            ph[j] = h; pm[j] = m; pl[j] = l;
        }
        const size_t base = ((size_t)(kb * 2 + nb) * 3) * 512 + (size_t)lane * 8;
        unsigned short* dst = wf + WF3_OFF;
        *(us8*)(dst + base)        = ph;
        *(us8*)(dst + base + 512)  = pm;
        *(us8*)(dst + base + 1024) = pl;
    }
}

// One wave computes one 32x32 output tile (all 32 batch rows x cols [32w,32w+32)).
// D layout (verified m74/m101): col(batch)=lane&31, row(channel)=(reg&3)+8*(reg>>2)+4*(lane>>5).
__device__ __forceinline__ void big_layer(const unsigned short* __restrict__ pb,
                                          const u32x4* __restrict__ wfL,
                                          const float* __restrict__ bias,
                                          int w, int lane, f32x16& acc)
{
    const int rb = lane & 31, hi = lane >> 5;
    #pragma unroll
    for (int g = 0; g < 4; ++g) {
        const f32x4 bv = *(const f32x4*)(bias + 32 * w + 8 * g + 4 * hi);
        #pragma unroll
        for (int rg = 0; rg < 4; ++rg) acc[4 * g + rg] = bv[rg];
    }
    #pragma unroll 2
    for (int ks = 0; ks < 16; ++ks) {
        us8 bb[3], aa[3];
        #pragma unroll
        for (int p = 0; p < 3; ++p) {
            bb[p] = __builtin_bit_cast(us8, wfL[((size_t)(ks * 8 + w) * 3 + p) * 64 + lane]);
            aa[p] = *(const us8*)(pb + (size_t)p * PS + (size_t)rb * PW + ks * 16 + hi * 8);
        }
        acc = mfma6w(bb, aa, acc);
    }
}

// __launch_bounds__(512, 6): 6 waves/EU -> 3 blocks/CU (register ceiling fix, R3).
__global__ __launch_bounds__(T, 6) void fused_mlp_topk(
    const float* __restrict__ x,
    const float* __restrict__ b1, const float* __restrict__ b2, const float* __restrict__ b3,
    const u32x4* __restrict__ wfrag, float* __restrict__ out)
{
    // Single 50688 B buffer; logits/selmask overlay it after the last pbuf read.
    __shared__ __align__(16) unsigned short pbuf[3][R][PW];

    const int t = threadIdx.x;
    const int lane = t & 63, w = t >> 6;     // wave id 0..7
    const int ln = lane & 15, q = lane >> 4; // 16x16 coords (layer 3)
    const int rb = lane & 31, hi = lane >> 5;// 32x32 coords (layers 1/2)
    const long row0 = (long)blockIdx.x * R;
    unsigned short* pb = &pbuf[0][0][0];
    float (*logitsB)[28] = (float (*)[28])pb;                 // 3584 B overlay
    unsigned* selmask = (unsigned*)(pb + 1792);               // +128 B overlay

    // ---- stage + split x once (coalesced f32x4 reads, b64 piece writes) ----
    #pragma unroll
    for (int it = 0; it < (R * D / 4) / T; ++it) {   // 4 iters
        const int idx = it * T + t;          // 0..2047 quads
        const int row = idx >> 6;
        const int c4 = (idx & 63) * 4;
        f32x4 v = *(const f32x4*)(x + (row0 + row) * D + c4);
        us4 ph, pm, pl;
        #pragma unroll
        for (int j = 0; j < 4; ++j) {
            unsigned short h, m, l; split3(v[j], h, m, l);
            ph[j] = h; pm[j] = m; pl[j] = l;
        }
        *(us4*)(pb + 0 * PS + (size_t)row * PW + c4) = ph;
        *(us4*)(pb + 1 * PS + (size_t)row * PW + c4) = pm;
        *(us4*)(pb + 2 * PS + (size_t)row * PW + c4) = pl;
    }
    __syncthreads();

    f32x16 acc;

    // ---- Layer 1 ----
    big_layer(pb, wfrag, b1, w, lane, acc);
    __syncthreads();         // all reads of x-pieces done
    // writeback: lane holds batch row rb; 4 runs of 4 consecutive channels
    #pragma unroll
    for (int g = 0; g < 4; ++g) {
        us4 ph, pm, pl;
        #pragma unroll
        for (int rg = 0; rg < 4; ++rg) {
            unsigned short h, m, l;
            split3(fmaxf(acc[4 * g + rg], 0.f), h, m, l);
            ph[rg] = h; pm[rg] = m; pl[rg] = l;
        }
        const size_t off = (size_t)rb * PW + 32 * w + 8 * g + 4 * hi;
        *(us4*)(pb + off)          = ph;
        *(us4*)(pb + PS + off)     = pm;
        *(us4*)(pb + 2 * PS + off) = pl;
    }
    __syncthreads();

    // ---- Layer 2 ----
    big_layer(pb, wfrag + WF2_OFF / 8, b2, w, lane, acc);
    __syncthreads();
    #pragma unroll
    for (int g = 0; g < 4; ++g) {
        us4 ph, pm, pl;
        #pragma unroll
        for (int rg = 0; rg < 4; ++rg) {
            unsigned short h, m, l;
            split3(fmaxf(acc[4 * g + rg], 0.f), h, m, l);
            ph[rg] = h; pm[rg] = m; pl[rg] = l;
        }
        const size_t off = (size_t)rb * PW + 32 * w + 8 * g + 4 * hi;
        *(us4*)(pb + off)          = ph;
        *(us4*)(pb + PS + off)     = pm;
        *(us4*)(pb + 2 * PS + off) = pl;
    }
    __syncthreads();

    // ---- Layer 3 (16x16 path, unchanged): waves 0..3 -> batch-tile (w&1), ch-tile (w>>1) ----
    const int rt3 = w & 1, nb3 = w >> 1;
    const int ch3 = nb3 * 16 + q * 4;        // channel base for this lane's 4 accs
    f32x4 a3;
    if (w < 4) {
        a3 = (ch3 < O) ? *(const f32x4*)(b3 + ch3) : (f32x4){0.f, 0.f, 0.f, 0.f};
        const u32x4* wf3 = wfrag + WF3_OFF / 8;
        #pragma unroll 2
        for (int kb = 0; kb < 8; ++kb) {
            us8 bb[3], aa[3];
            #pragma unroll
            for (int p = 0; p < 3; ++p) {
                bb[p] = __builtin_bit_cast(us8, wf3[((size_t)(kb * 2 + nb3) * 3 + p) * 64 + lane]);
                aa[p] = *(const us8*)(pb + (size_t)p * PS +
                                      (size_t)(rt3 * 16 + ln) * PW + kb * 32 + q * 8);
            }
            a3 = mfma6s(bb, aa, a3);
        }
    }
    __syncthreads();         // all pbuf reads done -> overlay region now writable

    if (w < 4 && ch3 < O) {
        *(f32x4*)(&logitsB[rt3 * 16 + ln][ch3]) = a3;
    }
    __syncthreads();

    // ---- top-6 of the 22 selected columns (cols != 0,12), one thread per row ----
    if (t < R) {
        float v[22];
        #pragma unroll
        for (int i = 0; i < 22; ++i) {
            const int j = (i < 11) ? (i + 1) : (i + 2);
            v[i] = logitsB[t][j];
        }
        unsigned taken = 0u;
        unsigned cm = 1u | (1u << 12);
        for (int kk = 0; kk < 6; ++kk) {
            float best = -3.4e38f; int bi = 0;
            #pragma unroll
            for (int i = 0; i < 22; ++i) {
                if (!((taken >> i) & 1u) && v[i] > best) { best = v[i]; bi = i; }
            }
            taken |= 1u << bi;
            cm |= 1u << ((bi < 11) ? (bi + 1) : (bi + 2));
        }
        selmask[t] = cm;
    }
    __syncthreads();

    // ---- write mask (coalesced) ----
    #pragma unroll
    for (int i = 0; i < 2; ++i) {
        const int idx = i * T + t;
        if (idx < R * O) {
            const int r = idx / O;
            const int j = idx - r * O;
            out[row0 * O + idx] = ((selmask[r] >> j) & 1u) ? 1.0f : 0.0f;
        }
    }
}

extern "C" void kernel_launch(void* const* d_in, const int* in_sizes, int n_in,
                              void* d_out, int out_size, void* d_ws, size_t ws_size,
                              hipStream_t stream) {
    const float* x  = (const float*)d_in[0];
    const float* W1 = (const float*)d_in[1];
    const float* b1 = (const float*)d_in[2];
    const float* W2 = (const float*)d_in[3];
    const float* b2 = (const float*)d_in[4];
    const float* W3 = (const float*)d_in[5];
    const float* b3 = (const float*)d_in[6];
    float* out = (float*)d_out;

    unsigned short* wf = (unsigned short*)d_ws;
    hipLaunchKernelGGL(split_w, dim3(272), dim3(64), 0, stream, W1, W2, W3, wf);

    const int B = in_sizes[0] / D;   // 131072
    const int nblk = B / R;          // 4096
    hipLaunchKernelGGL(fused_mlp_topk, dim3(nblk), dim3(T), 0, stream,
                       x, b1, b2, b3, (const u32x4*)d_ws, out);
}

// Round 7
// 355.534 us; speedup vs baseline: 1.0432x; 1.0432x over previous
//
#include <hip/hip_runtime.h>

#define D 256
#define H 256
#define O 24
#define R 32          // rows per block
#define T 512         // 8 waves; wave = 32 rows x 32 cols (2 row-tiles x 2 col-tiles)
#define PW 264        // bf16 row stride for piece buffers
#define PS (R * PW)   // piece stride in ushort

typedef __attribute__((ext_vector_type(4))) float f32x4;
typedef __attribute__((ext_vector_type(4))) unsigned short us4;
typedef __attribute__((ext_vector_type(8))) unsigned short us8;
typedef __attribute__((ext_vector_type(8))) __bf16 bf16x8;
typedef __attribute__((ext_vector_type(4))) unsigned int u32x4;

// d_ws layout (ushort units): tile(kb,nb) base = ((kb*NB+nb)*3)*512, pieces +0/+512/+1024
//   wf1 @ 0 (384 KB) | wf2 @ 196608 (384 KB) | wf3 @ 393216 (48 KB)
#define WF2_OFF 196608
#define WF3_OFF 393216

// Exact 3-piece bf16 split. (__bf16) cast = HW RNE (v_cvt_pk-class) — verified
// bit-identical to the manual add-shift RNE in R6 (absmax 0.0); residuals exact.
__device__ __forceinline__ void split3(float v, unsigned short& h, unsigned short& m,
                                       unsigned short& l) {
    __bf16 hb = (__bf16)v;
    float r = v - (float)hb;
    __bf16 mb = (__bf16)r;
    float r2 = r - (float)mb;
    __bf16 lb = (__bf16)r2;
    h = __builtin_bit_cast(unsigned short, hb);
    m = __builtin_bit_cast(unsigned short, mb);
    l = __builtin_bit_cast(unsigned short, lb);
}

__device__ __forceinline__ f32x4 mfma16(us8 a, us8 b, f32x4 c) {
    return __builtin_amdgcn_mfma_f32_16x16x32_bf16(
        __builtin_bit_cast(bf16x8, a), __builtin_bit_cast(bf16x8, b), c, 0, 0, 0);
}

// Operand-swapped 6-pass product (weights as A-operand, activations as B-operand).
// Covers all product terms >= ~2^-16 relative; matches fp32 to ~2^-27.
__device__ __forceinline__ f32x4 mfma6s(const us8* wgt, const us8* act, f32x4 c) {
    c = mfma16(wgt[0], act[0], c);
    c = mfma16(wgt[0], act[1], c);
    c = mfma16(wgt[0], act[2], c);
    c = mfma16(wgt[1], act[0], c);
    c = mfma16(wgt[1], act[1], c);
    c = mfma16(wgt[2], act[0], c);
    return c;
}

// ---- pre-split W1/W2/W3 into fragment-linear bf16 pieces (16x16x32 B-format) ----
__global__ __launch_bounds__(64) void split_w(
    const float* __restrict__ W1, const float* __restrict__ W2,
    const float* __restrict__ W3, unsigned short* __restrict__ wf)
{
    const int bid = blockIdx.x;        // 0..271
    const int lane = threadIdx.x;      // 0..63
    const int q = lane >> 4, ln = lane & 15;
    const float* src; unsigned short* dst; int nbcnt, ld, ncols, kb, nb;
    if (bid < 256) {
        int mat = bid >> 7; kb = (bid >> 4) & 7; nb = bid & 15;
        src = mat ? W2 : W1; dst = wf + (mat ? WF2_OFF : 0);
        nbcnt = 16; ld = H; ncols = H;
    } else {
        int b = bid - 256; kb = b >> 1; nb = b & 1;
        src = W3; dst = wf + WF3_OFF; nbcnt = 2; ld = O; ncols = O;
    }
    const int n = nb * 16 + ln;
    us8 ph, pm, pl;
    #pragma unroll
    for (int j = 0; j < 8; ++j) {
        const int k = kb * 32 + q * 8 + j;
        float v = (n < ncols) ? src[(size_t)k * ld + n] : 0.f;
        unsigned short h, m, l; split3(v, h, m, l);
        ph[j] = h; pm[j] = m; pl[j] = l;
    }
    const size_t base = ((size_t)(kb * nbcnt + nb) * 3) * 512 + (size_t)lane * 8;
    *(us8*)(dst + base)        = ph;
    *(us8*)(dst + base + 512)  = pm;
    *(us8*)(dst + base + 1024) = pl;
}

// One wave computes 32 rows x 2 col-tiles. Weights = A-operand, activations = B.
// D layout: row=channel(q*4+reg), col=batch(ln). A-frags loaded per-rt (12 live
// frag regs peak); 4 independent acc chains per kb for MFMA ILP. No setprio (R4).
__device__ __forceinline__ void big_layer(const unsigned short* __restrict__ pb,
                                          const u32x4* __restrict__ wfL,
                                          const float* __restrict__ bias,
                                          int nb0, int lane, f32x4 acc[2][2])
{
    const int ln = lane & 15, q = lane >> 4;
    #pragma unroll
    for (int nb = 0; nb < 2; ++nb) {
        const f32x4 bv = *(const f32x4*)(bias + (nb0 + nb) * 16 + q * 4);
        #pragma unroll
        for (int rt = 0; rt < 2; ++rt) acc[rt][nb] = bv;
    }
    #pragma unroll 2
    for (int kb = 0; kb < 8; ++kb) {
        us8 bb[2][3];
        #pragma unroll
        for (int nb = 0; nb < 2; ++nb)
            #pragma unroll
            for (int p = 0; p < 3; ++p)
                bb[nb][p] = __builtin_bit_cast(us8,
                    wfL[((size_t)(kb * 16 + nb0 + nb) * 3 + p) * 64 + lane]);
        #pragma unroll
        for (int rt = 0; rt < 2; ++rt) {
            us8 aa[3];
            #pragma unroll
            for (int p = 0; p < 3; ++p)
                aa[p] = *(const us8*)(pb + (size_t)p * PS +
                                      (size_t)(rt * 16 + ln) * PW + kb * 32 + q * 8);
            #pragma unroll
            for (int nb = 0; nb < 2; ++nb)
                acc[rt][nb] = mfma6s(bb[nb], aa, acc[rt][nb]);
        }
    }
}

// __launch_bounds__(512, 6): 6 waves/EU -> 3 blocks/CU (register ceiling fix, R3).
__global__ __launch_bounds__(T, 6) void fused_mlp_topk(
    const float* __restrict__ x,
    const float* __restrict__ b1, const float* __restrict__ b2, const float* __restrict__ b3,
    const u32x4* __restrict__ wfrag, float* __restrict__ out)
{
    // Single 50688 B buffer; logits/selmask overlay it after the last pbuf read.
    __shared__ __align__(16) unsigned short pbuf[3][R][PW];

    const int t = threadIdx.x;
    const int lane = t & 63, w = t >> 6;     // wave id 0..7
    const int ln = lane & 15, q = lane >> 4;
    const long row0 = (long)blockIdx.x * R;
    unsigned short* pb = &pbuf[0][0][0];
    float (*logitsB)[28] = (float (*)[28])pb;                 // 3584 B overlay, 16B-aligned rows
    unsigned* selmask = (unsigned*)(pb + 1792);               // +128 B overlay

    // ---- stage + split x once (coalesced f32x4 reads, b64 piece writes) ----
    #pragma unroll
    for (int it = 0; it < (R * D / 4) / T; ++it) {   // 4 iters
        const int idx = it * T + t;          // 0..2047 quads
        const int row = idx >> 6;
        const int c4 = (idx & 63) * 4;
        f32x4 v = *(const f32x4*)(x + (row0 + row) * D + c4);
        us4 ph, pm, pl;
        #pragma unroll
        for (int j = 0; j < 4; ++j) {
            unsigned short h, m, l; split3(v[j], h, m, l);
            ph[j] = h; pm[j] = m; pl[j] = l;
        }
        *(us4*)(pb + 0 * PS + (size_t)row * PW + c4) = ph;
        *(us4*)(pb + 1 * PS + (size_t)row * PW + c4) = pm;
        *(us4*)(pb + 2 * PS + (size_t)row * PW + c4) = pl;
    }
    __syncthreads();

    const int nb0 = 2 * w;   // this wave's two col-tiles
    f32x4 acc[2][2];

    // ---- Layer 1 ----
    big_layer(pb, wfrag, b1, nb0, lane, acc);
    __syncthreads();         // all reads of x-pieces done
    // writeback: lane holds 4 consecutive channels (q*4+rg) of batch row (rt*16+ln)
    #pragma unroll
    for (int rt = 0; rt < 2; ++rt)
        #pragma unroll
        for (int nb = 0; nb < 2; ++nb) {
            us4 ph, pm, pl;
            #pragma unroll
            for (int rg = 0; rg < 4; ++rg) {
                unsigned short h, m, l;
                split3(fmaxf(acc[rt][nb][rg], 0.f), h, m, l);
                ph[rg] = h; pm[rg] = m; pl[rg] = l;
            }
            const size_t off = (size_t)(rt * 16 + ln) * PW + (nb0 + nb) * 16 + q * 4;
            *(us4*)(pb + off)          = ph;
            *(us4*)(pb + PS + off)     = pm;
            *(us4*)(pb + 2 * PS + off) = pl;
        }
    __syncthreads();

    // ---- Layer 2 ----
    big_layer(pb, wfrag + WF2_OFF / 8, b2, nb0, lane, acc);
    __syncthreads();
    #pragma unroll
    for (int rt = 0; rt < 2; ++rt)
        #pragma unroll
        for (int nb = 0; nb < 2; ++nb) {
            us4 ph, pm, pl;
            #pragma unroll
            for (int rg = 0; rg < 4; ++rg) {
                unsigned short h, m, l;
                split3(fmaxf(acc[rt][nb][rg], 0.f), h, m, l);
                ph[rg] = h; pm[rg] = m; pl[rg] = l;
            }
            const size_t off = (size_t)(rt * 16 + ln) * PW + (nb0 + nb) * 16 + q * 4;
            *(us4*)(pb + off)          = ph;
            *(us4*)(pb + PS + off)     = pm;
            *(us4*)(pb + 2 * PS + off) = pl;
        }
    __syncthreads();

    // ---- Layer 3: waves 0..3 -> batch-tile (w&1), channel-tile (w>>1) ----
    const int rt3 = w & 1, nb3 = w >> 1;
    const int ch3 = nb3 * 16 + q * 4;        // channel base for this lane's 4 accs
    f32x4 a3;
    if (w < 4) {
        a3 = (ch3 < O) ? *(const f32x4*)(b3 + ch3) : (f32x4){0.f, 0.f, 0.f, 0.f};
        const u32x4* wf3 = wfrag + WF3_OFF / 8;
        #pragma unroll 2
        for (int kb = 0; kb < 8; ++kb) {
            us8 bb[3], aa[3];
            #pragma unroll
            for (int p = 0; p < 3; ++p) {
                bb[p] = __builtin_bit_cast(us8, wf3[((size_t)(kb * 2 + nb3) * 3 + p) * 64 + lane]);
                aa[p] = *(const us8*)(pb + (size_t)p * PS +
                                      (size_t)(rt3 * 16 + ln) * PW + kb * 32 + q * 8);
            }
            a3 = mfma6s(bb, aa, a3);
        }
    }
    __syncthreads();         // all pbuf reads done -> overlay region now writable

    if (w < 4 && ch3 < O) {
        // 4 consecutive channels of batch row rt3*16+ln -> one f32x4 store
        *(f32x4*)(&logitsB[rt3 * 16 + ln][ch3]) = a3;
    }
    __syncthreads();

    // ---- top-6 of the 22 selected columns (cols != 0,12), one thread per row ----
    if (t < R) {
        float v[22];
        #pragma unroll
        for (int i = 0; i < 22; ++i) {
            const int j = (i < 11) ? (i + 1) : (i + 2);
            v[i] = logitsB[t][j];
        }
        unsigned taken = 0u;
        unsigned cm = 1u | (1u << 12);
        for (int kk = 0; kk < 6; ++kk) {
            float best = -3.4e38f; int bi = 0;
            #pragma unroll
            for (int i = 0; i < 22; ++i) {
                if (!((taken >> i) & 1u) && v[i] > best) { best = v[i]; bi = i; }
            }
            taken |= 1u << bi;
            cm |= 1u << ((bi < 11) ? (bi + 1) : (bi + 2));
        }
        selmask[t] = cm;
    }
    __syncthreads();

    // ---- write mask (coalesced) ----
    #pragma unroll
    for (int i = 0; i < 2; ++i) {
        const int idx = i * T + t;
        if (idx < R * O) {
            const int r = idx / O;
            const int j = idx - r * O;
            out[row0 * O + idx] = ((selmask[r] >> j) & 1u) ? 1.0f : 0.0f;
        }
    }
}

extern "C" void kernel_launch(void* const* d_in, const int* in_sizes, int n_in,
                              void* d_out, int out_size, void* d_ws, size_t ws_size,
                              hipStream_t stream) {
    const float* x  = (const float*)d_in[0];
    const float* W1 = (const float*)d_in[1];
    const float* b1 = (const float*)d_in[2];
    const float* W2 = (const float*)d_in[3];
    const float* b2 = (const float*)d_in[4];
    const float* W3 = (const float*)d_in[5];
    const float* b3 = (const float*)d_in[6];
    float* out = (float*)d_out;

    unsigned short* wf = (unsigned short*)d_ws;
    hipLaunchKernelGGL(split_w, dim3(272), dim3(64), 0, stream, W1, W2, W3, wf);

    const int B = in_sizes[0] / D;   // 131072
    const int nblk = B / R;          // 4096
    hipLaunchKernelGGL(fused_mlp_topk, dim3(nblk), dim3(T), 0, stream,
                       x, b1, b2, b3, (const u32x4*)d_ws, out);
}